// Round 1
// baseline (539.069 us; speedup 1.0000x reference)
//
#include <hip/hip_runtime.h>
#include <stdint.h>
#include <stddef.h>

#define BM 128
#define BN 128
#define BK 64

typedef __bf16 bf16x8 __attribute__((ext_vector_type(8)));
typedef float floatx4 __attribute__((ext_vector_type(4)));

// round-to-nearest-even f32 -> bf16 bits
__device__ inline unsigned short f2bf(float f) {
    union { float f; unsigned int u; } v; v.f = f;
    unsigned int u = v.u;
    unsigned int r = (u + 0x7fffu + ((u >> 16) & 1u)) >> 16;
    return (unsigned short)r;
}

__global__ void cvt_f32_to_bf16(const float* __restrict__ in,
                                unsigned short* __restrict__ out, int n4) {
    int i = blockIdx.x * blockDim.x + threadIdx.x;
    int stride = gridDim.x * blockDim.x;
    for (int idx = i; idx < n4; idx += stride) {
        float4 f = ((const float4*)in)[idx];
        ushort4 o;
        o.x = f2bf(f.x); o.y = f2bf(f.y); o.z = f2bf(f.z); o.w = f2bf(f.w);
        ((ushort4*)out)[idx] = o;
    }
}

// y[m,n] = sum_k A[m,k]*B[n,k] + bias[n]
// A: [M,K] bf16 bits, B: [N,K] bf16 bits (both K-major), C: [M,N] fp32
__global__ void gemm_bt_bias(const unsigned short* __restrict__ A,
                             const unsigned short* __restrict__ B,
                             const float* __restrict__ bias,
                             float* __restrict__ C,
                             int M, int N, int K) {
    __shared__ __align__(16) unsigned short As[BM * BK]; // 16 KB
    __shared__ __align__(16) unsigned short Bs[BN * BK]; // 16 KB

    const int tid  = threadIdx.x;
    const int lane = tid & 63;
    const int wave = tid >> 6;          // 0..3

    const int bm = blockIdx.y * BM;
    const int bn = blockIdx.x * BN;

    // --- staging setup: 16 chunks of 1 KB per tile; wave w owns chunks w*4..w*4+3.
    // HW writes lane's 16 B at (wave-uniform lds base) + lane*16.
    const unsigned short* gA[4];
    const unsigned short* gB[4];
    const unsigned short* lA[4];
    const unsigned short* lB[4];
#pragma unroll
    for (int i = 0; i < 4; ++i) {
        int c   = wave * 4 + i;
        int e   = c * 512 + lane * 8;   // bf16 element offset within tile
        int row = e >> 6;               // /64
        int col = e & 63;
        gA[i] = A + (size_t)(bm + row) * K + col;
        gB[i] = B + (size_t)(bn + row) * K + col;
        lA[i] = As + c * 512;           // lane-independent (wave-uniform) base
        lB[i] = Bs + c * 512;
    }

    const int lr = lane & 15;           // row(A-frag) / col(B-frag) / out col
    const int lq = lane >> 4;           // quad

    const int wm = (wave >> 1) * 64;    // wave's sub-tile origin
    const int wn = (wave & 1) * 64;

    floatx4 acc[4][4];
#pragma unroll
    for (int mi = 0; mi < 4; ++mi)
#pragma unroll
        for (int ni = 0; ni < 4; ++ni)
            acc[mi][ni] = (floatx4){0.f, 0.f, 0.f, 0.f};

    for (int k0 = 0; k0 < K; k0 += BK) {
#pragma unroll
        for (int i = 0; i < 4; ++i) {
            __builtin_amdgcn_global_load_lds(
                (const __attribute__((address_space(1))) void*)(gA[i]),
                (__attribute__((address_space(3))) void*)(lA[i]), 16, 0, 0);
            __builtin_amdgcn_global_load_lds(
                (const __attribute__((address_space(1))) void*)(gB[i]),
                (__attribute__((address_space(3))) void*)(lB[i]), 16, 0, 0);
            gA[i] += BK;
            gB[i] += BK;
        }
        __syncthreads();   // compiler emits vmcnt(0) drain before barrier

#pragma unroll
        for (int ks = 0; ks < 2; ++ks) {
            bf16x8 af[4], bfr[4];
#pragma unroll
            for (int mi = 0; mi < 4; ++mi)
                af[mi] = *(const bf16x8*)(As + (wm + mi * 16 + lr) * BK + ks * 32 + lq * 8);
#pragma unroll
            for (int ni = 0; ni < 4; ++ni)
                bfr[ni] = *(const bf16x8*)(Bs + (wn + ni * 16 + lr) * BK + ks * 32 + lq * 8);
#pragma unroll
            for (int mi = 0; mi < 4; ++mi)
#pragma unroll
                for (int ni = 0; ni < 4; ++ni)
                    acc[mi][ni] = __builtin_amdgcn_mfma_f32_16x16x32_bf16(
                        af[mi], bfr[ni], acc[mi][ni], 0, 0, 0);
        }
        __syncthreads();
    }

    // epilogue: C[m][n] = acc + bias[n]; C/D layout col=lane&15, row=quad*4+reg
#pragma unroll
    for (int ni = 0; ni < 4; ++ni) {
        int n = bn + wn + ni * 16 + lr;
        float bv = bias[n];
#pragma unroll
        for (int mi = 0; mi < 4; ++mi) {
            int m0 = bm + wm + mi * 16 + lq * 4;
#pragma unroll
            for (int r = 0; r < 4; ++r) {
                C[(size_t)(m0 + r) * N + n] = acc[mi][ni][r] + bv;
            }
        }
    }
}

extern "C" void kernel_launch(void* const* d_in, const int* in_sizes, int n_in,
                              void* d_out, int out_size, void* d_ws, size_t ws_size,
                              hipStream_t stream) {
    const float* x    = (const float*)d_in[0];  // [M,K]
    const float* w    = (const float*)d_in[1];  // [N,K]
    const float* bias = (const float*)d_in[2];  // [N]
    float* out = (float*)d_out;

    const int N = in_sizes[2];             // 4096
    const int K = in_sizes[1] / N;         // 4096
    const int M = in_sizes[0] / K;         // 8192

    unsigned short* xb = (unsigned short*)d_ws;              // [M,K] bf16
    unsigned short* wb = xb + (size_t)M * K;                 // [N,K] bf16

    cvt_f32_to_bf16<<<4096, 256, 0, stream>>>(x, xb, (M * K) / 4);
    cvt_f32_to_bf16<<<4096, 256, 0, stream>>>(w, wb, (N * K) / 4);

    dim3 grid(N / BN, M / BM);
    gemm_bt_bias<<<grid, 256, 0, stream>>>(xb, wb, bias, out, M, N, K);
}